// Round 10
// baseline (192.868 us; speedup 1.0000x reference)
//
#include <hip/hip_runtime.h>
#include <hip/hip_fp16.h>

#define BB 2
#define NN 1024
#define MM 1024
#define DD 256
#define HH 128
#define C2LE 2.8853900817779268f       // 2*log2(e)
#define NEG2LOG2E -2.8853900817779268f // -2*log2(e)
#define SHIFT_C -4.3280860f            // -3*log2(e): P = e^{s-3}, softmax-invariant
#define REPS 3                         // attribution experiment: x3 inner repeat

typedef float v2f __attribute__((ext_vector_type(2)));
typedef float v4f __attribute__((ext_vector_type(4)));
typedef _Float16 h8 __attribute__((ext_vector_type(8)));

// ---- Kernel 1: e = exp2(C*(x@W + bias)).  A-side -> EaT[b][h][n] (transposed)
// B-side -> Eb[b][m][h] (row-major).
__global__ __launch_bounds__(256) void proj_kernel(
    const float* __restrict__ query, const float* __restrict__ key,
    const float* __restrict__ Wa_w, const float* __restrict__ Wa_b,
    const float* __restrict__ Wb_w, const float* __restrict__ Wb_b,
    float* __restrict__ EaT, float* __restrict__ Eb) {
    __shared__ float rows[8][DD];     // 8KB
    __shared__ float partial[8][HH];  // 4KB
    const int tid = threadIdx.x;
    const int rb = blockIdx.x * 8;
    const bool isA = rb < BB * NN;
    const float* in = isA ? query : key;
    const float* W  = isA ? Wa_w : Wb_w;
    const float* bias = isA ? Wa_b : Wb_b;
    const int base = isA ? rb : rb - BB * NN;

#pragma unroll 1
    for (int rep = 0; rep < REPS; ++rep) {
        asm volatile("" ::: "memory");
        __syncthreads();
        const float4* in4 = (const float4*)(in + (size_t)base * DD);
        float4* rows4 = (float4*)rows;
        rows4[tid] = in4[tid];
        rows4[tid + 256] = in4[tid + 256];
        __syncthreads();

        const int h = tid & 127, half = tid >> 7;
        const int d0 = half * 128;
        float acc[8] = {};
        for (int d = d0; d < d0 + 128; d += 4) {
            const float w0 = W[(d + 0) * HH + h];
            const float w1 = W[(d + 1) * HH + h];
            const float w2 = W[(d + 2) * HH + h];
            const float w3 = W[(d + 3) * HH + h];
#pragma unroll
            for (int r = 0; r < 8; ++r) {
                const float4 rv = *(const float4*)&rows[r][d];
                acc[r] = fmaf(rv.x, w0, fmaf(rv.y, w1, fmaf(rv.z, w2, fmaf(rv.w, w3, acc[r]))));
            }
        }
        if (half) {
#pragma unroll
            for (int r = 0; r < 8; ++r) partial[r][h] = acc[r];
        }
        __syncthreads();
        if (!half) {
            const float bv = bias[h];
            float ev[8];
#pragma unroll
            for (int r = 0; r < 8; ++r)
                ev[r] = __builtin_amdgcn_exp2f(C2LE * (acc[r] + partial[r][h] + bv));
            if (isA) {
                const int bq = base >> 10, nb = base & (NN - 1);
                float* dst = EaT + ((size_t)(bq * HH + h)) * NN + nb;
                *(float4*)dst = *(float4*)&ev[0];
                *(float4*)(dst + 4) = *(float4*)&ev[4];
            } else {
#pragma unroll
                for (int r = 0; r < 8; ++r)
                    Eb[(size_t)(base + r) * HH + h] = ev[r];
            }
        }
    }
}

// ---- Kernel 1b: KT_hi/lo[b][d][m] = f16 split of key[b][m][d] (transposed)
__global__ __launch_bounds__(256) void convert_kernel(
    const float* __restrict__ key, __half* __restrict__ KT_hi,
    __half* __restrict__ KT_lo) {
    __shared__ float t[64][65];
    const int tid = threadIdx.x;
    const int m0 = blockIdx.x * 64, d0 = blockIdx.y * 64, b = blockIdx.z;
#pragma unroll 1
    for (int rep = 0; rep < REPS; ++rep) {
        asm volatile("" ::: "memory");
        __syncthreads();
        for (int i = tid; i < 1024; i += 256) {
            const int r = i >> 4, c4 = i & 15;
            const float4 v =
                *(const float4*)&key[((size_t)(b * MM + m0 + r)) * DD + d0 + c4 * 4];
            t[r][c4 * 4 + 0] = v.x; t[r][c4 * 4 + 1] = v.y;
            t[r][c4 * 4 + 2] = v.z; t[r][c4 * 4 + 3] = v.w;
        }
        __syncthreads();
        for (int i = tid; i < 4096; i += 256) {
            const int dr = i >> 6, mc = i & 63;
            const float f = t[mc][dr];
            const __half hi = __float2half(f);
            const __half lo = __float2half(f - __half2float(hi));
            const size_t o = ((size_t)(b * DD + d0 + dr)) * MM + m0 + mc;
            KT_hi[o] = hi;
            KT_lo[o] = lo;
        }
    }
}

// ---- Kernel 2: Ph[b,n,m] = f16( exp(-2*sum_h v_h/(Ea*Eb+1) - 3) ) +
//      per-64m-chunk row sums psum[mq][b][n]. 4 h-terms share one rcp.
__global__ __launch_bounds__(256) void scores_kernel(
    const float* __restrict__ EaT, const float* __restrict__ Eb,
    const float* __restrict__ v_w, __half* __restrict__ Ph,
    float* __restrict__ psum) {
    __shared__ float b_s[64 * HH];  // 32KB, XOR-swizzled (slot ^ row&31)
    const int tid = threadIdx.x;
    const int mq = blockIdx.x;
    const int m0 = mq * 64, n0 = blockIdx.y * 32, b = blockIdx.z;

#pragma unroll 1
    for (int rep = 0; rep < REPS; ++rep) {
        asm volatile("" ::: "memory");
        __syncthreads();
        for (int i = tid; i < 64 * 32; i += 256) {
            const int r = i >> 5, h4 = i & 31;
            *(float4*)&b_s[r * HH + ((h4 ^ (r & 31)) << 2)] =
                *(const float4*)&Eb[((size_t)(b * MM + m0 + r)) * HH + h4 * 4];
        }
        __syncthreads();

        const int ml = tid & 63;
        const int ng = __builtin_amdgcn_readfirstlane(threadIdx.x >> 6);
        const int mlx = ml & 31;
        const float* brow = &b_s[ml * HH];
        const float* aT = EaT + (size_t)b * HH * NN + (n0 + ng * 8);
        v2f acc[4] = {};
        for (int h4 = 0; h4 < 32; ++h4) {
            const float4 b4 = *(const float4*)&brow[(h4 ^ mlx) << 2];  // per-lane LDS
            const float4 w4 = *(const float4*)&v_w[h4 * 4];            // uniform
            const float* a0p = aT + (size_t)(h4 * 4 + 0) * NN;
            const float* a1p = aT + (size_t)(h4 * 4 + 1) * NN;
            const float* a2p = aT + (size_t)(h4 * 4 + 2) * NN;
            const float* a3p = aT + (size_t)(h4 * 4 + 3) * NN;
#pragma unroll
            for (int np = 0; np < 4; ++np) {
                const v2f a0 = *(const v2f*)&a0p[np * 2];  // uniform pairs
                const v2f a1 = *(const v2f*)&a1p[np * 2];
                const v2f a2 = *(const v2f*)&a2p[np * 2];
                const v2f a3 = *(const v2f*)&a3p[np * 2];
                const v2f u0 = a0 * b4.x + 1.0f;
                const v2f u1 = a1 * b4.y + 1.0f;
                const v2f u2 = a2 * b4.z + 1.0f;
                const v2f u3 = a3 * b4.w + 1.0f;
                const v2f p01 = u0 * u1, p23 = u2 * u3;
                const v2f An = w4.x * u1 + w4.y * u0;
                const v2f Bn = w4.z * u3 + w4.w * u2;
                const v2f num = An * p23 + Bn * p01;
                const v2f Pp = p01 * p23;
                v2f r2;
                r2.x = __builtin_amdgcn_rcpf(Pp.x);
                r2.y = __builtin_amdgcn_rcpf(Pp.y);
                acc[np] = num * r2 + acc[np];
            }
        }

        float pv[8];
#pragma unroll
        for (int np = 0; np < 4; ++np) {
            pv[np * 2 + 0] = __builtin_amdgcn_exp2f(fmaf(acc[np].x, NEG2LOG2E, SHIFT_C));
            pv[np * 2 + 1] = __builtin_amdgcn_exp2f(fmaf(acc[np].y, NEG2LOG2E, SHIFT_C));
        }
        const size_t prow = ((size_t)b * NN + n0 + ng * 8) * MM + m0 + ml;
#pragma unroll
        for (int j = 0; j < 8; ++j) {
            Ph[prow + (size_t)j * MM] = __float2half(pv[j]);
            float s = pv[j];
#pragma unroll
            for (int o = 32; o > 0; o >>= 1) s += __shfl_xor(s, o);
            if (ml == 0)
                psum[((size_t)mq * BB + b) * NN + n0 + ng * 8 + j] = s;
        }
    }
}

// ---- Kernel 3: out[n,d] = (P @ K) / rowsum via MFMA 16x16x32 f16.
// Block 32n x 64d, 8 waves of 16n x 16d; K = hi + lo f16 split (fp32-grade).
__global__ __launch_bounds__(512) void attend_kernel(
    const __half* __restrict__ Ph, const __half* __restrict__ KT_hi,
    const __half* __restrict__ KT_lo, const float* __restrict__ psum,
    float* __restrict__ out) {
    __shared__ float inv[32];
    const int tid = threadIdx.x;
    const int n0 = blockIdx.x * 32, d0 = blockIdx.y * 64, b = blockIdx.z;

    if (tid < 32) {
        float s = 0.f;
#pragma unroll
        for (int q = 0; q < 16; ++q)
            s += psum[((size_t)q * BB + b) * NN + n0 + tid];
        inv[tid] = __builtin_amdgcn_rcpf(s);
    }
    __syncthreads();

    const int wave = __builtin_amdgcn_readfirstlane(threadIdx.x >> 6);
    const int lane = tid & 63;
    const int nh = wave >> 2, dh = wave & 3;
    const int row16 = lane & 15, kg = lane >> 4;

#pragma unroll 1
    for (int rep = 0; rep < REPS; ++rep) {
        asm volatile("" ::: "memory");
        const h8* Ap = (const h8*)(Ph + ((size_t)(b * NN + n0 + nh * 16 + row16)) * MM + kg * 8);
        const h8* Bh = (const h8*)(KT_hi + ((size_t)(b * DD + d0 + dh * 16 + row16)) * MM + kg * 8);
        const h8* Bl = (const h8*)(KT_lo + ((size_t)(b * DD + d0 + dh * 16 + row16)) * MM + kg * 8);

        v4f ch = {0.f, 0.f, 0.f, 0.f}, cl = {0.f, 0.f, 0.f, 0.f};
        h8 a0 = Ap[0], bh0 = Bh[0], bl0 = Bl[0];
#pragma unroll 4
        for (int it = 0; it < 31; ++it) {
            const h8 a1 = Ap[(it + 1) * 4];
            const h8 bh1 = Bh[(it + 1) * 4];
            const h8 bl1 = Bl[(it + 1) * 4];
            ch = __builtin_amdgcn_mfma_f32_16x16x32_f16(a0, bh0, ch, 0, 0, 0);
            cl = __builtin_amdgcn_mfma_f32_16x16x32_f16(a0, bl0, cl, 0, 0, 0);
            a0 = a1; bh0 = bh1; bl0 = bl1;
        }
        ch = __builtin_amdgcn_mfma_f32_16x16x32_f16(a0, bh0, ch, 0, 0, 0);
        cl = __builtin_amdgcn_mfma_f32_16x16x32_f16(a0, bl0, cl, 0, 0, 0);

        const int rbase = nh * 16 + kg * 4;
#pragma unroll
        for (int r = 0; r < 4; ++r) {
            const float v = (ch[r] + cl[r]) * inv[rbase + r];
            out[((size_t)(b * NN + n0 + rbase + r)) * DD + d0 + dh * 16 + row16] = v;
        }
    }
}

extern "C" void kernel_launch(void* const* d_in, const int* in_sizes, int n_in,
                              void* d_out, int out_size, void* d_ws, size_t ws_size,
                              hipStream_t stream) {
    const float* query = (const float*)d_in[0];
    const float* key   = (const float*)d_in[1];
    const float* Wa_w  = (const float*)d_in[2];
    const float* Wa_b  = (const float*)d_in[3];
    const float* Wb_w  = (const float*)d_in[4];
    const float* Wb_b  = (const float*)d_in[5];
    const float* v_w   = (const float*)d_in[6];
    float* out = (float*)d_out;

    float* ws = (float*)d_ws;
    float* EaT  = ws;                          // BB*HH*NN f32
    float* Eb   = EaT + BB * NN * HH;          // BB*MM*HH f32
    float* psum = Eb + BB * MM * HH;           // 16*BB*NN f32
    __half* Ph    = (__half*)(psum + 16 * BB * NN);       // BB*NN*MM f16
    __half* KT_hi = Ph + (size_t)BB * NN * MM;            // BB*DD*MM f16
    __half* KT_lo = KT_hi + (size_t)BB * DD * MM;         // BB*DD*MM f16

    proj_kernel<<<dim3((BB * NN + BB * MM) / 8), dim3(256), 0, stream>>>(
        query, key, Wa_w, Wa_b, Wb_w, Wb_b, EaT, Eb);
    convert_kernel<<<dim3(MM / 64, DD / 64, BB), dim3(256), 0, stream>>>(
        key, KT_hi, KT_lo);
    scores_kernel<<<dim3(MM / 64, NN / 32, BB), dim3(256), 0, stream>>>(
        EaT, Eb, v_w, Ph, psum);
    attend_kernel<<<dim3(NN / 32, DD / 64, BB), dim3(512), 0, stream>>>(
        Ph, KT_hi, KT_lo, psum, out);
}

// Round 11
// 115.665 us; speedup vs baseline: 1.6675x; 1.6675x over previous
//
#include <hip/hip_runtime.h>
#include <hip/hip_fp16.h>

#define BB 2
#define NN 1024
#define MM 1024
#define DD 256
#define HH 128
#define C2LE 2.8853900817779268f       // 2*log2(e)
#define NEG2LOG2E -2.8853900817779268f // -2*log2(e)
#define SHIFT_C -4.3280860f            // -3*log2(e): P = e^{s-3}, softmax-invariant
#define REPS_ATT 3                     // attribution: x3 on attend only

typedef float v2f __attribute__((ext_vector_type(2)));
typedef float v4f __attribute__((ext_vector_type(4)));
typedef _Float16 h8 __attribute__((ext_vector_type(8)));

// ---- Kernel 1: e = exp2(C*(x@W + bias)).  A-side -> EaT[b][h][n] (transposed)
// B-side -> Eb[b][m][h] (row-major).
__global__ __launch_bounds__(256) void proj_kernel(
    const float* __restrict__ query, const float* __restrict__ key,
    const float* __restrict__ Wa_w, const float* __restrict__ Wa_b,
    const float* __restrict__ Wb_w, const float* __restrict__ Wb_b,
    float* __restrict__ EaT, float* __restrict__ Eb) {
    __shared__ float rows[8][DD];     // 8KB
    __shared__ float partial[8][HH];  // 4KB
    const int tid = threadIdx.x;
    const int rb = blockIdx.x * 8;
    const bool isA = rb < BB * NN;
    const float* in = isA ? query : key;
    const float* W  = isA ? Wa_w : Wb_w;
    const float* bias = isA ? Wa_b : Wb_b;
    const int base = isA ? rb : rb - BB * NN;

    const float4* in4 = (const float4*)(in + (size_t)base * DD);
    float4* rows4 = (float4*)rows;
    rows4[tid] = in4[tid];
    rows4[tid + 256] = in4[tid + 256];
    __syncthreads();

    const int h = tid & 127, half = tid >> 7;
    const int d0 = half * 128;
    float acc[8] = {};
    for (int d = d0; d < d0 + 128; d += 4) {
        const float w0 = W[(d + 0) * HH + h];
        const float w1 = W[(d + 1) * HH + h];
        const float w2 = W[(d + 2) * HH + h];
        const float w3 = W[(d + 3) * HH + h];
#pragma unroll
        for (int r = 0; r < 8; ++r) {
            const float4 rv = *(const float4*)&rows[r][d];
            acc[r] = fmaf(rv.x, w0, fmaf(rv.y, w1, fmaf(rv.z, w2, fmaf(rv.w, w3, acc[r]))));
        }
    }
    if (half) {
#pragma unroll
        for (int r = 0; r < 8; ++r) partial[r][h] = acc[r];
    }
    __syncthreads();
    if (!half) {
        const float bv = bias[h];
        float ev[8];
#pragma unroll
        for (int r = 0; r < 8; ++r)
            ev[r] = __builtin_amdgcn_exp2f(C2LE * (acc[r] + partial[r][h] + bv));
        if (isA) {
            const int bq = base >> 10, nb = base & (NN - 1);
            float* dst = EaT + ((size_t)(bq * HH + h)) * NN + nb;
            *(float4*)dst = *(float4*)&ev[0];
            *(float4*)(dst + 4) = *(float4*)&ev[4];
        } else {
#pragma unroll
            for (int r = 0; r < 8; ++r)
                Eb[(size_t)(base + r) * HH + h] = ev[r];
        }
    }
}

// ---- Kernel 1b: KT_hi/lo[b][d][m] = f16 split of key[b][m][d] (transposed)
__global__ __launch_bounds__(256) void convert_kernel(
    const float* __restrict__ key, __half* __restrict__ KT_hi,
    __half* __restrict__ KT_lo) {
    __shared__ float t[64][65];
    const int tid = threadIdx.x;
    const int m0 = blockIdx.x * 64, d0 = blockIdx.y * 64, b = blockIdx.z;
    for (int i = tid; i < 1024; i += 256) {
        const int r = i >> 4, c4 = i & 15;
        const float4 v =
            *(const float4*)&key[((size_t)(b * MM + m0 + r)) * DD + d0 + c4 * 4];
        t[r][c4 * 4 + 0] = v.x; t[r][c4 * 4 + 1] = v.y;
        t[r][c4 * 4 + 2] = v.z; t[r][c4 * 4 + 3] = v.w;
    }
    __syncthreads();
    for (int i = tid; i < 4096; i += 256) {
        const int dr = i >> 6, mc = i & 63;
        const float f = t[mc][dr];
        const __half hi = __float2half(f);
        const __half lo = __float2half(f - __half2float(hi));
        const size_t o = ((size_t)(b * DD + d0 + dr)) * MM + m0 + mc;
        KT_hi[o] = hi;
        KT_lo[o] = lo;
    }
}

// ---- Kernel 2: Ph[b,n,m] = f16( exp(-2*sum_h v_h/(Ea*Eb+1) - 3) ) +
//      per-64m-chunk row sums psum[mq][b][n]. 4 h-terms share one rcp.
__global__ __launch_bounds__(256) void scores_kernel(
    const float* __restrict__ EaT, const float* __restrict__ Eb,
    const float* __restrict__ v_w, __half* __restrict__ Ph,
    float* __restrict__ psum) {
    __shared__ float b_s[64 * HH];  // 32KB, XOR-swizzled (slot ^ row&31)
    const int tid = threadIdx.x;
    const int mq = blockIdx.x;
    const int m0 = mq * 64, n0 = blockIdx.y * 32, b = blockIdx.z;

    for (int i = tid; i < 64 * 32; i += 256) {
        const int r = i >> 5, h4 = i & 31;
        *(float4*)&b_s[r * HH + ((h4 ^ (r & 31)) << 2)] =
            *(const float4*)&Eb[((size_t)(b * MM + m0 + r)) * HH + h4 * 4];
    }
    __syncthreads();

    const int ml = tid & 63;
    const int ng = __builtin_amdgcn_readfirstlane(threadIdx.x >> 6);
    const int mlx = ml & 31;
    const float* brow = &b_s[ml * HH];
    const float* aT = EaT + (size_t)b * HH * NN + (n0 + ng * 8);
    v2f acc[4] = {};
    for (int h4 = 0; h4 < 32; ++h4) {
        const float4 b4 = *(const float4*)&brow[(h4 ^ mlx) << 2];  // per-lane LDS
        const float4 w4 = *(const float4*)&v_w[h4 * 4];            // uniform
        const float* a0p = aT + (size_t)(h4 * 4 + 0) * NN;
        const float* a1p = aT + (size_t)(h4 * 4 + 1) * NN;
        const float* a2p = aT + (size_t)(h4 * 4 + 2) * NN;
        const float* a3p = aT + (size_t)(h4 * 4 + 3) * NN;
#pragma unroll
        for (int np = 0; np < 4; ++np) {
            const v2f a0 = *(const v2f*)&a0p[np * 2];  // uniform pairs
            const v2f a1 = *(const v2f*)&a1p[np * 2];
            const v2f a2 = *(const v2f*)&a2p[np * 2];
            const v2f a3 = *(const v2f*)&a3p[np * 2];
            const v2f u0 = a0 * b4.x + 1.0f;
            const v2f u1 = a1 * b4.y + 1.0f;
            const v2f u2 = a2 * b4.z + 1.0f;
            const v2f u3 = a3 * b4.w + 1.0f;
            const v2f p01 = u0 * u1, p23 = u2 * u3;
            const v2f An = w4.x * u1 + w4.y * u0;
            const v2f Bn = w4.z * u3 + w4.w * u2;
            const v2f num = An * p23 + Bn * p01;
            const v2f Pp = p01 * p23;
            v2f r2;
            r2.x = __builtin_amdgcn_rcpf(Pp.x);
            r2.y = __builtin_amdgcn_rcpf(Pp.y);
            acc[np] = num * r2 + acc[np];
        }
    }

    float pv[8];
#pragma unroll
    for (int np = 0; np < 4; ++np) {
        pv[np * 2 + 0] = __builtin_amdgcn_exp2f(fmaf(acc[np].x, NEG2LOG2E, SHIFT_C));
        pv[np * 2 + 1] = __builtin_amdgcn_exp2f(fmaf(acc[np].y, NEG2LOG2E, SHIFT_C));
    }
    const size_t prow = ((size_t)b * NN + n0 + ng * 8) * MM + m0 + ml;
#pragma unroll
    for (int j = 0; j < 8; ++j) {
        Ph[prow + (size_t)j * MM] = __float2half(pv[j]);
        float s = pv[j];
#pragma unroll
        for (int o = 32; o > 0; o >>= 1) s += __shfl_xor(s, o);
        if (ml == 0)
            psum[((size_t)mq * BB + b) * NN + n0 + ng * 8 + j] = s;
    }
}

// ---- Kernel 3 v2: out = (P @ K)/rowsum via MFMA. 64n x 64d per block,
// grid 128 (all co-resident). XCD-group swizzle: all 16 n-blocks of one
// (d0,b) land on one XCD -> its 256KB KT slice stays L2-resident.
__global__ __launch_bounds__(256) void attend_kernel(
    const __half* __restrict__ Ph, const __half* __restrict__ KT_hi,
    const __half* __restrict__ KT_lo, const float* __restrict__ psum,
    float* __restrict__ out) {
    __shared__ float inv[64];
    const int bid = blockIdx.x;
    const int swz = (bid & 7) * 16 + (bid >> 3);  // bijective, 128 blocks
    const int x = swz & 15, yz = swz >> 4;        // yz = d-block*2 + b? (0..7)
    const int n0 = x * 64, d0 = (yz & 3) * 64, b = yz >> 2;
    const int tid = threadIdx.x;

    if (tid < 64) {
        float s = 0.f;
#pragma unroll
        for (int q = 0; q < 16; ++q)
            s += psum[((size_t)q * BB + b) * NN + n0 + tid];
        inv[tid] = __builtin_amdgcn_rcpf(s);
    }
    __syncthreads();

    const int wave = __builtin_amdgcn_readfirstlane(threadIdx.x >> 6);
    const int lane = tid & 63;
    const int nh = wave >> 1, dh = wave & 1;  // 2x2 waves of 32n x 32d
    const int row16 = lane & 15, kg = lane >> 4;

    const h8* A0 = (const h8*)(Ph + ((size_t)(b * NN + n0 + nh * 32 + row16)) * MM + kg * 8);
    const h8* A1 = (const h8*)(Ph + ((size_t)(b * NN + n0 + nh * 32 + 16 + row16)) * MM + kg * 8);
    const h8* BH0 = (const h8*)(KT_hi + ((size_t)(b * DD + d0 + dh * 32 + row16)) * MM + kg * 8);
    const h8* BH1 = (const h8*)(KT_hi + ((size_t)(b * DD + d0 + dh * 32 + 16 + row16)) * MM + kg * 8);
    const h8* BL0 = (const h8*)(KT_lo + ((size_t)(b * DD + d0 + dh * 32 + row16)) * MM + kg * 8);
    const h8* BL1 = (const h8*)(KT_lo + ((size_t)(b * DD + d0 + dh * 32 + 16 + row16)) * MM + kg * 8);

#pragma unroll 1
    for (int rep = 0; rep < REPS_ATT; ++rep) {
        asm volatile("" ::: "memory");
        v4f c00h = {0,0,0,0}, c01h = c00h, c10h = c00h, c11h = c00h;
        v4f c00l = c00h, c01l = c00h, c10l = c00h, c11l = c00h;
#pragma unroll 2
        for (int it = 0; it < 32; ++it) {
            const h8 a0 = A0[it * 4];
            const h8 a1 = A1[it * 4];
            const h8 bh0 = BH0[it * 4];
            const h8 bh1 = BH1[it * 4];
            const h8 bl0 = BL0[it * 4];
            const h8 bl1 = BL1[it * 4];
            c00h = __builtin_amdgcn_mfma_f32_16x16x32_f16(a0, bh0, c00h, 0, 0, 0);
            c01h = __builtin_amdgcn_mfma_f32_16x16x32_f16(a0, bh1, c01h, 0, 0, 0);
            c10h = __builtin_amdgcn_mfma_f32_16x16x32_f16(a1, bh0, c10h, 0, 0, 0);
            c11h = __builtin_amdgcn_mfma_f32_16x16x32_f16(a1, bh1, c11h, 0, 0, 0);
            c00l = __builtin_amdgcn_mfma_f32_16x16x32_f16(a0, bl0, c00l, 0, 0, 0);
            c01l = __builtin_amdgcn_mfma_f32_16x16x32_f16(a0, bl1, c01l, 0, 0, 0);
            c10l = __builtin_amdgcn_mfma_f32_16x16x32_f16(a1, bl0, c10l, 0, 0, 0);
            c11l = __builtin_amdgcn_mfma_f32_16x16x32_f16(a1, bl1, c11l, 0, 0, 0);
        }

        const v4f cs[2][2] = {{c00h + c00l, c01h + c01l},
                              {c10h + c10l, c11h + c11l}};
#pragma unroll
        for (int t = 0; t < 2; ++t) {
#pragma unroll
            for (int u = 0; u < 2; ++u) {
#pragma unroll
                for (int r = 0; r < 4; ++r) {
                    const int nrow = nh * 32 + t * 16 + kg * 4 + r;
                    out[((size_t)(b * NN + n0 + nrow)) * DD + d0 + dh * 32 +
                        u * 16 + row16] = cs[t][u][r] * inv[nrow];
                }
            }
        }
    }
}

extern "C" void kernel_launch(void* const* d_in, const int* in_sizes, int n_in,
                              void* d_out, int out_size, void* d_ws, size_t ws_size,
                              hipStream_t stream) {
    const float* query = (const float*)d_in[0];
    const float* key   = (const float*)d_in[1];
    const float* Wa_w  = (const float*)d_in[2];
    const float* Wa_b  = (const float*)d_in[3];
    const float* Wb_w  = (const float*)d_in[4];
    const float* Wb_b  = (const float*)d_in[5];
    const float* v_w   = (const float*)d_in[6];
    float* out = (float*)d_out;

    float* ws = (float*)d_ws;
    float* EaT  = ws;                          // BB*HH*NN f32
    float* Eb   = EaT + BB * NN * HH;          // BB*MM*HH f32
    float* psum = Eb + BB * MM * HH;           // 16*BB*NN f32
    __half* Ph    = (__half*)(psum + 16 * BB * NN);       // BB*NN*MM f16
    __half* KT_hi = Ph + (size_t)BB * NN * MM;            // BB*DD*MM f16
    __half* KT_lo = KT_hi + (size_t)BB * DD * MM;         // BB*DD*MM f16

    proj_kernel<<<dim3((BB * NN + BB * MM) / 8), dim3(256), 0, stream>>>(
        query, key, Wa_w, Wa_b, Wb_w, Wb_b, EaT, Eb);
    convert_kernel<<<dim3(MM / 64, DD / 64, BB), dim3(256), 0, stream>>>(
        key, KT_hi, KT_lo);
    scores_kernel<<<dim3(MM / 64, NN / 32, BB), dim3(256), 0, stream>>>(
        EaT, Eb, v_w, Ph, psum);
    attend_kernel<<<dim3(128), dim3(256), 0, stream>>>(
        Ph, KT_hi, KT_lo, psum, out);
}

// Round 12
// 73.462 us; speedup vs baseline: 2.6254x; 1.5745x over previous
//
#include <hip/hip_runtime.h>
#include <hip/hip_fp16.h>

#define BB 2
#define NN 1024
#define MM 1024
#define DD 256
#define HH 128
#define C2LE 2.8853900817779268f       // 2*log2(e)
#define NEG2LOG2E -2.8853900817779268f // -2*log2(e)
#define SHIFT_C -4.3280860f            // -3*log2(e): P = e^{s-3}, softmax-invariant

typedef float v2f __attribute__((ext_vector_type(2)));
typedef float v4f __attribute__((ext_vector_type(4)));
typedef _Float16 h8 __attribute__((ext_vector_type(8)));

// ---- Kernel 1: blocks <512: e = exp2(C*(x@W+bias)) -> EaT (A, transposed) /
// Eb (B, row-major). blocks >=512: KT_hi/lo[b][d][m] = f16 split of key^T.
__global__ __launch_bounds__(256) void proj_conv_kernel(
    const float* __restrict__ query, const float* __restrict__ key,
    const float* __restrict__ Wa_w, const float* __restrict__ Wa_b,
    const float* __restrict__ Wb_w, const float* __restrict__ Wb_b,
    float* __restrict__ EaT, float* __restrict__ Eb,
    __half* __restrict__ KT_hi, __half* __restrict__ KT_lo) {
    __shared__ float rows[8][DD];     // 8KB (proj)
    __shared__ float partial[8][HH];  // 4KB (proj)
    __shared__ float t[64][65];       // 16.25KB (convert)
    const int tid = threadIdx.x;

    if (blockIdx.x >= 512) {  // ---- convert branch (uniform per block)
        const int cid = blockIdx.x - 512;
        const int m0 = (cid & 15) * 64, d0 = ((cid >> 4) & 3) * 64, b = cid >> 6;
        for (int i = tid; i < 1024; i += 256) {
            const int r = i >> 4, c4 = i & 15;
            const float4 v =
                *(const float4*)&key[((size_t)(b * MM + m0 + r)) * DD + d0 + c4 * 4];
            t[r][c4 * 4 + 0] = v.x; t[r][c4 * 4 + 1] = v.y;
            t[r][c4 * 4 + 2] = v.z; t[r][c4 * 4 + 3] = v.w;
        }
        __syncthreads();
        for (int i = tid; i < 4096; i += 256) {
            const int dr = i >> 6, mc = i & 63;
            const float f = t[mc][dr];
            const __half hi = __float2half(f);
            const __half lo = __float2half(f - __half2float(hi));
            const size_t o = ((size_t)(b * DD + d0 + dr)) * MM + m0 + mc;
            KT_hi[o] = hi;
            KT_lo[o] = lo;
        }
        return;
    }

    const int rb = blockIdx.x * 8;
    const bool isA = rb < BB * NN;
    const float* in = isA ? query : key;
    const float* W  = isA ? Wa_w : Wb_w;
    const float* bias = isA ? Wa_b : Wb_b;
    const int base = isA ? rb : rb - BB * NN;

    const float4* in4 = (const float4*)(in + (size_t)base * DD);
    float4* rows4 = (float4*)rows;
    rows4[tid] = in4[tid];
    rows4[tid + 256] = in4[tid + 256];
    __syncthreads();

    const int h = tid & 127, half = tid >> 7;
    const int d0 = half * 128;
    float acc[8] = {};
    for (int d = d0; d < d0 + 128; d += 4) {
        const float w0 = W[(d + 0) * HH + h];
        const float w1 = W[(d + 1) * HH + h];
        const float w2 = W[(d + 2) * HH + h];
        const float w3 = W[(d + 3) * HH + h];
#pragma unroll
        for (int r = 0; r < 8; ++r) {
            const float4 rv = *(const float4*)&rows[r][d];
            acc[r] = fmaf(rv.x, w0, fmaf(rv.y, w1, fmaf(rv.z, w2, fmaf(rv.w, w3, acc[r]))));
        }
    }
    if (half) {
#pragma unroll
        for (int r = 0; r < 8; ++r) partial[r][h] = acc[r];
    }
    __syncthreads();
    if (!half) {
        const float bv = bias[h];
        float ev[8];
#pragma unroll
        for (int r = 0; r < 8; ++r)
            ev[r] = __builtin_amdgcn_exp2f(C2LE * (acc[r] + partial[r][h] + bv));
        if (isA) {
            const int bq = base >> 10, nb = base & (NN - 1);
            float* dst = EaT + ((size_t)(bq * HH + h)) * NN + nb;
            *(float4*)dst = *(float4*)&ev[0];
            *(float4*)(dst + 4) = *(float4*)&ev[4];
        } else {
#pragma unroll
            for (int r = 0; r < 8; ++r)
                Eb[(size_t)(base + r) * HH + h] = ev[r];
        }
    }
}

// ---- Kernel 2: Ph[b,n,m] = f16( exp(-2*sum_h v_h/(Ea*Eb+1) - 3) ) +
//      per-64m-chunk row sums psum[mq][b][n]. 4 h-terms share one rcp.
//      a-tile staged in LDS -> uniform ds_read_b64 broadcasts (no VMEM).
__global__ __launch_bounds__(256) void scores_kernel(
    const float* __restrict__ EaT, const float* __restrict__ Eb,
    const float* __restrict__ v_w, __half* __restrict__ Ph,
    float* __restrict__ psum) {
    __shared__ float b_s[64 * HH];   // 32KB, XOR-swizzled (slot ^ row&31)
    __shared__ float a_s[HH * 32];   // 16KB, [h][n]
    const int tid = threadIdx.x;
    const int mq = blockIdx.x;
    const int m0 = mq * 64, n0 = blockIdx.y * 32, b = blockIdx.z;

    for (int i = tid; i < 64 * 32; i += 256) {
        const int r = i >> 5, h4 = i & 31;
        *(float4*)&b_s[r * HH + ((h4 ^ (r & 31)) << 2)] =
            *(const float4*)&Eb[((size_t)(b * MM + m0 + r)) * HH + h4 * 4];
    }
    for (int i = tid; i < 128 * 8; i += 256) {
        const int hh = i >> 3, n4 = i & 7;
        *(float4*)&a_s[hh * 32 + n4 * 4] =
            *(const float4*)&EaT[((size_t)(b * HH + hh)) * NN + n0 + n4 * 4];
    }
    __syncthreads();

    const int ml = tid & 63;
    const int ng = __builtin_amdgcn_readfirstlane(threadIdx.x >> 6);
    const int mlx = ml & 31;
    const float* brow = &b_s[ml * HH];
    const float* as = &a_s[ng * 8];  // wave-uniform base
    v2f acc[4] = {};
    for (int h4 = 0; h4 < 32; ++h4) {
        const float4 b4 = *(const float4*)&brow[(h4 ^ mlx) << 2];  // per-lane LDS
        const float4 w4 = *(const float4*)&v_w[h4 * 4];            // uniform
        const float* ap = as + h4 * 4 * 32;
#pragma unroll
        for (int np = 0; np < 4; ++np) {
            const v2f a0 = *(const v2f*)&ap[0 * 32 + np * 2];  // LDS broadcasts
            const v2f a1 = *(const v2f*)&ap[1 * 32 + np * 2];
            const v2f a2 = *(const v2f*)&ap[2 * 32 + np * 2];
            const v2f a3 = *(const v2f*)&ap[3 * 32 + np * 2];
            const v2f u0 = a0 * b4.x + 1.0f;
            const v2f u1 = a1 * b4.y + 1.0f;
            const v2f u2 = a2 * b4.z + 1.0f;
            const v2f u3 = a3 * b4.w + 1.0f;
            const v2f p01 = u0 * u1, p23 = u2 * u3;
            const v2f An = w4.x * u1 + w4.y * u0;
            const v2f Bn = w4.z * u3 + w4.w * u2;
            const v2f num = An * p23 + Bn * p01;
            const v2f Pp = p01 * p23;
            v2f r2;
            r2.x = __builtin_amdgcn_rcpf(Pp.x);
            r2.y = __builtin_amdgcn_rcpf(Pp.y);
            acc[np] = num * r2 + acc[np];
        }
    }

    float pv[8];
#pragma unroll
    for (int np = 0; np < 4; ++np) {
        pv[np * 2 + 0] = __builtin_amdgcn_exp2f(fmaf(acc[np].x, NEG2LOG2E, SHIFT_C));
        pv[np * 2 + 1] = __builtin_amdgcn_exp2f(fmaf(acc[np].y, NEG2LOG2E, SHIFT_C));
    }
    const size_t prow = ((size_t)b * NN + n0 + ng * 8) * MM + m0 + ml;
#pragma unroll
    for (int j = 0; j < 8; ++j) {
        Ph[prow + (size_t)j * MM] = __float2half(pv[j]);
        float s = pv[j];
#pragma unroll
        for (int o = 32; o > 0; o >>= 1) s += __shfl_xor(s, o);
        if (ml == 0)
            psum[((size_t)mq * BB + b) * NN + n0 + ng * 8 + j] = s;
    }
}

// ---- Kernel 3 v3: partial[kh] = P[:, kh-half] @ K[kh-half, :] via MFMA.
// 1024 blocks (4 waves, 16n x 16d tiles, k=512) = 4 waves/SIMD. Depth-2
// register prefetch. XCD swizzle: each XCD owns 8 (b,nt) combos x all d,k.
__global__ __launch_bounds__(256) void attend_kernel(
    const __half* __restrict__ Ph, const __half* __restrict__ KT_hi,
    const __half* __restrict__ KT_lo, float* __restrict__ partial) {
    const int bid = blockIdx.x;
    const int xcd = bid & 7, c = bid >> 3;
    const int dt = c & 7, kh = (c >> 3) & 1, nb = c >> 4;
    const int ncombo = xcd * 8 + nb;
    const int b = ncombo >> 5, nt = ncombo & 31;
    const int n0 = nt * 32, d0 = dt * 32, m0 = kh * 512;

    const int tid = threadIdx.x;
    const int wave = __builtin_amdgcn_readfirstlane(threadIdx.x >> 6);
    const int lane = tid & 63;
    const int nh = wave >> 1, dh = wave & 1;
    const int row16 = lane & 15, kg = lane >> 4;

    const h8* A = (const h8*)(Ph + ((size_t)(b * NN + n0 + nh * 16 + row16)) * MM + m0 + kg * 8);
    const h8* BH = (const h8*)(KT_hi + ((size_t)(b * DD + d0 + dh * 16 + row16)) * MM + m0 + kg * 8);
    const h8* BL = (const h8*)(KT_lo + ((size_t)(b * DD + d0 + dh * 16 + row16)) * MM + m0 + kg * 8);

    v4f ch = {0.f, 0.f, 0.f, 0.f}, cl = ch;
    h8 a0 = A[0], bh0 = BH[0], bl0 = BL[0];
    h8 a1 = A[4], bh1 = BH[4], bl1 = BL[4];
#pragma unroll 1
    for (int it = 0; it < 14; it += 2) {
        const h8 a2 = A[(it + 2) * 4];
        const h8 bh2 = BH[(it + 2) * 4];
        const h8 bl2 = BL[(it + 2) * 4];
        const h8 a3 = A[(it + 3) * 4];
        const h8 bh3 = BH[(it + 3) * 4];
        const h8 bl3 = BL[(it + 3) * 4];
        ch = __builtin_amdgcn_mfma_f32_16x16x32_f16(a0, bh0, ch, 0, 0, 0);
        cl = __builtin_amdgcn_mfma_f32_16x16x32_f16(a0, bl0, cl, 0, 0, 0);
        ch = __builtin_amdgcn_mfma_f32_16x16x32_f16(a1, bh1, ch, 0, 0, 0);
        cl = __builtin_amdgcn_mfma_f32_16x16x32_f16(a1, bl1, cl, 0, 0, 0);
        a0 = a2; bh0 = bh2; bl0 = bl2;
        a1 = a3; bh1 = bh3; bl1 = bl3;
    }
    ch = __builtin_amdgcn_mfma_f32_16x16x32_f16(a0, bh0, ch, 0, 0, 0);
    cl = __builtin_amdgcn_mfma_f32_16x16x32_f16(a0, bl0, cl, 0, 0, 0);
    ch = __builtin_amdgcn_mfma_f32_16x16x32_f16(a1, bh1, ch, 0, 0, 0);
    cl = __builtin_amdgcn_mfma_f32_16x16x32_f16(a1, bl1, cl, 0, 0, 0);

    float* pp = partial +
        (((size_t)kh * BB + b) * NN + n0 + nh * 16 + kg * 4) * DD + d0 + dh * 16 + row16;
#pragma unroll
    for (int r = 0; r < 4; ++r) pp[(size_t)r * DD] = ch[r] + cl[r];
}

// ---- Kernel 4: out[b,n,d] = (partial[0]+partial[1]) / sum_q psum[q][b][n]
__global__ __launch_bounds__(256) void combine_kernel(
    const float* __restrict__ partial, const float* __restrict__ psum,
    float* __restrict__ out) {
    const int n = blockIdx.x, b = blockIdx.y, d = threadIdx.x;
    float s = 0.f;
#pragma unroll
    for (int q = 0; q < 16; ++q)
        s += psum[((size_t)q * BB + b) * NN + n];
    const size_t off = ((size_t)b * NN + n) * DD + d;
    const float a =
        partial[off] + partial[(size_t)BB * NN * DD + off];
    out[off] = a * __builtin_amdgcn_rcpf(s);
}

extern "C" void kernel_launch(void* const* d_in, const int* in_sizes, int n_in,
                              void* d_out, int out_size, void* d_ws, size_t ws_size,
                              hipStream_t stream) {
    const float* query = (const float*)d_in[0];
    const float* key   = (const float*)d_in[1];
    const float* Wa_w  = (const float*)d_in[2];
    const float* Wa_b  = (const float*)d_in[3];
    const float* Wb_w  = (const float*)d_in[4];
    const float* Wb_b  = (const float*)d_in[5];
    const float* v_w   = (const float*)d_in[6];
    float* out = (float*)d_out;

    float* ws = (float*)d_ws;
    float* EaT  = ws;                          // BB*HH*NN f32
    float* Eb   = EaT + BB * NN * HH;          // BB*MM*HH f32
    float* psum = Eb + BB * MM * HH;           // 16*BB*NN f32
    __half* Ph    = (__half*)(psum + 16 * BB * NN);   // BB*NN*MM f16
    __half* KT_hi = Ph + (size_t)BB * NN * MM;        // BB*DD*MM f16
    __half* KT_lo = KT_hi + (size_t)BB * DD * MM;     // BB*DD*MM f16
    float* partial = (float*)(KT_lo + (size_t)BB * DD * MM);  // 2*BB*NN*DD f32

    proj_conv_kernel<<<dim3(512 + 128), dim3(256), 0, stream>>>(
        query, key, Wa_w, Wa_b, Wb_w, Wb_b, EaT, Eb, KT_hi, KT_lo);
    scores_kernel<<<dim3(MM / 64, NN / 32, BB), dim3(256), 0, stream>>>(
        EaT, Eb, v_w, Ph, psum);
    attend_kernel<<<dim3(1024), dim3(256), 0, stream>>>(
        Ph, KT_hi, KT_lo, partial);
    combine_kernel<<<dim3(NN, BB), dim3(256), 0, stream>>>(
        partial, psum, out);
}